// Round 3
// baseline (200.120 us; speedup 1.0000x reference)
//
#include <hip/hip_runtime.h>

#define BB 16
#define AA 3
#define CC 80
#define NT 256

// noobj: one thread per cell. 403200 cells / 256 = 1575 blocks exactly.
// Block ranges align exactly with scale boundaries:
//   blocks [0,1200)    -> p0 (307200 cells)
//   blocks [1200,1500) -> p1 (76800 cells)
//   blocks [1500,1575) -> p2 (19200 cells)
#define NOOBJ_BLOCKS 1575
#define TOTAL_BLOCKS (NOOBJ_BLOCKS + 3)

__device__ __forceinline__ float sigf(float x){ return 1.f/(1.f+expf(-x)); }
__device__ __forceinline__ float clogf_(float p){ return fmaxf(logf(p), -100.f); }

// block(256) reduce -> total valid on thread 0
__device__ __forceinline__ float block_reduce(float v){
    #pragma unroll
    for (int o = 32; o > 0; o >>= 1) v += __shfl_down(v, o, 64);
    __shared__ float wsum[4];
    int lane = threadIdx.x & 63;
    int wid  = threadIdx.x >> 6;
    if (lane == 0) wsum[wid] = v;
    __syncthreads();
    return wsum[0] + wsum[1] + wsum[2] + wsum[3];
}

__global__ void yolo_main_kernel(const float* __restrict__ p0, const float* __restrict__ p1,
                                 const float* __restrict__ p2, const float* __restrict__ anchors,
                                 const float* __restrict__ targets, float* __restrict__ ws){
    float partial = 0.f;

    if (blockIdx.x < NOOBJ_BLOCKS) {
        // ---- noobj: -0.5 * clog(1 - sigmoid(ch4)), one cell per thread ----
        // Tensor select is block-uniform (no divergence), one load per thread.
        int i = blockIdx.x * 256 + threadIdx.x;
        const float* p; int cell;
        if (blockIdx.x < 1200)      { p = p0; cell = i; }
        else if (blockIdx.x < 1500) { p = p1; cell = i - 307200; }
        else                        { p = p2; cell = i - 384000; }
        float x = p[(size_t)cell * 85 + 4];
        // log(1-sigmoid(x)) = -softplus(x); overflow -> -inf -> clamped -100
        float term = fmaxf(-log1pf(expf(x)), -100.f);
        partial = block_reduce(term) * -0.5f;
    } else {
        // ---- targets: one block per scale, one thread per target ----
        int s = blockIdx.x - NOOBJ_BLOCKS;
        int g = (s == 0) ? 80 : ((s == 1) ? 40 : 20);
        const float* pred = (s == 0) ? p0 : ((s == 1) ? p1 : p2);
        float stride = 640.f / (float)g;
        int t = threadIdx.x;

        float x = targets[t*6 + 2] * (float)g;
        float y = targets[t*6 + 3] * (float)g;
        float w = targets[t*6 + 4] * 640.f;
        float h = targets[t*6 + 5] * 640.f;
        int bi = (int)targets[t*6 + 0];
        int ci = (int)targets[t*6 + 1];

        bool valid = (x >= 0.f) && (y >= 0.f) && (x <= (float)(g-1)) && (y <= (float)(g-1));
        int gx = (int)floorf(x), gy = (int)floorf(y);

        // argmax IoU over 3 anchors, first max wins (matches jnp.argmax)
        float best_iou = -1.f, saw = 1.f, sah = 1.f; int besti = 0;
        #pragma unroll
        for (int a = 0; a < 3; a++){
            float aw = anchors[s*6 + a*2 + 0] * stride;
            float ah = anchors[s*6 + a*2 + 1] * stride;
            float inter = fminf(w, aw) * fminf(h, ah);
            float iou = inter / (w*h + aw*ah - inter + 1e-16f);
            if (iou > best_iou){ best_iou = iou; besti = a; saw = aw; sah = ah; }
        }

        // last-write-wins dedup (XLA scatter-set ordering)
        __shared__ int skey[NT];
        int key = valid ? (((bi*AA + besti)*g + gy)*g + gx) : -1;
        skey[t] = key;
        __syncthreads();
        bool owner = valid;
        if (valid){
            for (int t2 = t + 1; t2 < NT; t2++){
                if (skey[t2] == key){ owner = false; break; }
            }
        }

        float acc = 0.f;
        if (owner){
            const float* pc = pred + (size_t)key * 85;
            float txv = x - (float)gx;
            float tyv = y - (float)gy;
            float twv = logf(w/saw + 1e-16f);
            float thv = logf(h/sah + 1e-16f);
            float px = sigf(pc[0]); acc += (px - txv)*(px - txv);
            float py = sigf(pc[1]); acc += (py - tyv)*(py - tyv);
            float dw = pc[2] - twv; acc += dw*dw;
            float dh = pc[3] - thv; acc += dh*dh;
            float pobj = sigf(pc[4]);
            acc += -clogf_(pobj);                               // obj term
            acc += 0.5f*fmaxf(-log1pf(expf(pc[4])), -100.f);    // cancel noobj count here
            for (int c = 0; c < CC; c++){
                float pcv = sigf(pc[5 + c]);
                acc += -((c == ci) ? clogf_(pcv) : clogf_(1.f - pcv));
            }
        }
        partial = block_reduce(acc);
    }

    if (threadIdx.x == 0) ws[blockIdx.x] = partial;
}

// Final reduce: 1 block, 256 threads grid-stride over 1578 partials
__global__ void yolo_final_kernel(const float* __restrict__ ws, float* __restrict__ out){
    float v = 0.f;
    for (int j = threadIdx.x; j < TOTAL_BLOCKS; j += 256) v += ws[j];
    float s = block_reduce(v);
    if (threadIdx.x == 0) out[0] = s;
}

extern "C" void kernel_launch(void* const* d_in, const int* in_sizes, int n_in,
                              void* d_out, int out_size, void* d_ws, size_t ws_size,
                              hipStream_t stream) {
    const float* p0      = (const float*)d_in[0];
    const float* p1      = (const float*)d_in[1];
    const float* p2      = (const float*)d_in[2];
    const float* anchors = (const float*)d_in[3];
    const float* targets = (const float*)d_in[4];
    float* out = (float*)d_out;
    float* ws  = (float*)d_ws;

    yolo_main_kernel<<<TOTAL_BLOCKS, 256, 0, stream>>>(p0, p1, p2, anchors, targets, ws);
    yolo_final_kernel<<<1, 256, 0, stream>>>(ws, out);
}

// Round 4
// 186.593 us; speedup vs baseline: 1.0725x; 1.0725x over previous
//
#include <hip/hip_runtime.h>

#define BB 16
#define AA 3
#define CC 80
#define NT 256

// noobj: 403200 cells = 525 blocks x 256 threads x 3 cells/thread.
// Scale boundaries align to 768-cell block chunks:
//   blocks [0,400)   -> p0 (307200 cells = 400*768)
//   blocks [400,500) -> p1 ( 76800 cells = 100*768)
//   blocks [500,525) -> p2 ( 19200 cells =  25*768)
#define NOOBJ_BLOCKS 525
#define TOTAL_BLOCKS (NOOBJ_BLOCKS + 3)

__device__ __forceinline__ float sigf(float x){ return 1.f/(1.f+expf(-x)); }
__device__ __forceinline__ float clogf_(float p){ return fmaxf(logf(p), -100.f); }

// block(256) reduce -> total valid on thread 0
__device__ __forceinline__ float block_reduce(float v){
    #pragma unroll
    for (int o = 32; o > 0; o >>= 1) v += __shfl_down(v, o, 64);
    __shared__ float wsum[4];
    int lane = threadIdx.x & 63;
    int wid  = threadIdx.x >> 6;
    if (lane == 0) wsum[wid] = v;
    __syncthreads();
    return wsum[0] + wsum[1] + wsum[2] + wsum[3];
}

__global__ void yolo_main_kernel(const float* __restrict__ p0, const float* __restrict__ p1,
                                 const float* __restrict__ p2, const float* __restrict__ anchors,
                                 const float* __restrict__ targets, float* __restrict__ ws){
    float partial = 0.f;

    if (blockIdx.x < NOOBJ_BLOCKS) {
        // ---- noobj: -0.5 * clog(1 - sigmoid(ch4)), 3 cells/thread (ILP=3) ----
        // Block-uniform tensor select; 3 independent strided loads in flight.
        const float* p; int base;
        if (blockIdx.x < 400)      { p = p0; base = blockIdx.x * 768; }
        else if (blockIdx.x < 500) { p = p1; base = blockIdx.x * 768 - 307200; }
        else                       { p = p2; base = blockIdx.x * 768 - 384000; }
        int c0 = base + threadIdx.x;
        float x0 = p[(size_t)(c0      ) * 85 + 4];
        float x1 = p[(size_t)(c0 + 256) * 85 + 4];
        float x2 = p[(size_t)(c0 + 512) * 85 + 4];
        // log(1-sigmoid(x)) = -softplus(x); overflow -> -inf -> clamped -100
        float acc = fmaxf(-log1pf(expf(x0)), -100.f)
                  + fmaxf(-log1pf(expf(x1)), -100.f)
                  + fmaxf(-log1pf(expf(x2)), -100.f);
        partial = block_reduce(acc) * -0.5f;
    } else {
        // ---- targets: one block per scale, one thread per target ----
        int s = blockIdx.x - NOOBJ_BLOCKS;
        int g = (s == 0) ? 80 : ((s == 1) ? 40 : 20);
        const float* pred = (s == 0) ? p0 : ((s == 1) ? p1 : p2);
        float stride = 640.f / (float)g;
        int t = threadIdx.x;

        float x = targets[t*6 + 2] * (float)g;
        float y = targets[t*6 + 3] * (float)g;
        float w = targets[t*6 + 4] * 640.f;
        float h = targets[t*6 + 5] * 640.f;
        int bi = (int)targets[t*6 + 0];
        int ci = (int)targets[t*6 + 1];

        bool valid = (x >= 0.f) && (y >= 0.f) && (x <= (float)(g-1)) && (y <= (float)(g-1));
        int gx = (int)floorf(x), gy = (int)floorf(y);

        // argmax IoU over 3 anchors, first max wins (matches jnp.argmax)
        float best_iou = -1.f, saw = 1.f, sah = 1.f; int besti = 0;
        #pragma unroll
        for (int a = 0; a < 3; a++){
            float aw = anchors[s*6 + a*2 + 0] * stride;
            float ah = anchors[s*6 + a*2 + 1] * stride;
            float inter = fminf(w, aw) * fminf(h, ah);
            float iou = inter / (w*h + aw*ah - inter + 1e-16f);
            if (iou > best_iou){ best_iou = iou; besti = a; saw = aw; sah = ah; }
        }

        // last-write-wins dedup (XLA scatter-set ordering)
        __shared__ int skey[NT];
        int key = valid ? (((bi*AA + besti)*g + gy)*g + gx) : -1;
        skey[t] = key;
        __syncthreads();
        bool owner = valid;
        if (valid){
            for (int t2 = t + 1; t2 < NT; t2++){
                if (skey[t2] == key){ owner = false; break; }
            }
        }

        float acc = 0.f;
        if (owner){
            const float* pc = pred + (size_t)key * 85;
            float txv = x - (float)gx;
            float tyv = y - (float)gy;
            float twv = logf(w/saw + 1e-16f);
            float thv = logf(h/sah + 1e-16f);
            float px = sigf(pc[0]); acc += (px - txv)*(px - txv);
            float py = sigf(pc[1]); acc += (py - tyv)*(py - tyv);
            float dw = pc[2] - twv; acc += dw*dw;
            float dh = pc[3] - thv; acc += dh*dh;
            float pobj = sigf(pc[4]);
            acc += -clogf_(pobj);                               // obj term
            acc += 0.5f*fmaxf(-log1pf(expf(pc[4])), -100.f);    // cancel noobj count here
            for (int c = 0; c < CC; c++){
                float pcv = sigf(pc[5 + c]);
                acc += -((c == ci) ? clogf_(pcv) : clogf_(1.f - pcv));
            }
        }
        partial = block_reduce(acc);
    }

    if (threadIdx.x == 0) ws[blockIdx.x] = partial;
}

// Final reduce: 1 block, 256 threads over 528 partials
__global__ void yolo_final_kernel(const float* __restrict__ ws, float* __restrict__ out){
    int t = threadIdx.x;
    float v = ws[t] + ws[t + 256];
    if (t < TOTAL_BLOCKS - 512) v += ws[t + 512];
    float s = block_reduce(v);
    if (t == 0) out[0] = s;
}

extern "C" void kernel_launch(void* const* d_in, const int* in_sizes, int n_in,
                              void* d_out, int out_size, void* d_ws, size_t ws_size,
                              hipStream_t stream) {
    const float* p0      = (const float*)d_in[0];
    const float* p1      = (const float*)d_in[1];
    const float* p2      = (const float*)d_in[2];
    const float* anchors = (const float*)d_in[3];
    const float* targets = (const float*)d_in[4];
    float* out = (float*)d_out;
    float* ws  = (float*)d_ws;

    yolo_main_kernel<<<TOTAL_BLOCKS, 256, 0, stream>>>(p0, p1, p2, anchors, targets, ws);
    yolo_final_kernel<<<1, 256, 0, stream>>>(ws, out);
}